// Round 9
// baseline (287.878 us; speedup 1.0000x reference)
//
#include <hip/hip_runtime.h>
#include <stdint.h>

typedef unsigned short u16;
typedef __attribute__((ext_vector_type(8))) short short8;
typedef __attribute__((ext_vector_type(4))) short sh4;
typedef __attribute__((ext_vector_type(4))) float f32x4;

#define MFMA16(a,b,c) __builtin_amdgcn_mfma_f32_16x16x32_bf16((a),(b),(c),0,0,0)

__device__ __forceinline__ u16 f2bf(float f) {
  union { float f; uint32_t u; } c; c.f = f;
  uint32_t u = c.u;
  return (u16)((u + 0x7fffu + ((u >> 16) & 1u)) >> 16);
}

__device__ __forceinline__ float fast_exp2(float x) {
#if __has_builtin(__builtin_amdgcn_exp2f)
  return __builtin_amdgcn_exp2f(x);
#else
  return __expf(x * 0.69314718056f);
#endif
}

// async global->LDS, 16B per lane; LDS dest = wave-uniform base + lane*16
__device__ __forceinline__ void async_cp16(const void* g, void* l) {
  __builtin_amdgcn_global_load_lds((__attribute__((address_space(1))) void*)g,
                                   (__attribute__((address_space(3))) void*)l,
                                   16, 0, 0);
}

// ---------------- fused prep: cvt x -> bf16; transpose Wp, Wo (64x64 tiles) ------
__global__ __launch_bounds__(256) void prep(const float* __restrict__ x,
                                            const float* __restrict__ Wp,
                                            const float* __restrict__ Wo,
                                            u16* __restrict__ x_bf,
                                            u16* __restrict__ WpT,
                                            u16* __restrict__ WoT) {
  int bx = blockIdx.x;
  int t = threadIdx.x;
  if (bx < 4096) {
    int i = bx * 256 + t;
    float4 v = ((const float4*)x)[i];
    ushort4 o; o.x = f2bf(v.x); o.y = f2bf(v.y); o.z = f2bf(v.z); o.w = f2bf(v.w);
    ((ushort4*)x_bf)[i] = o;
    return;
  }
  __shared__ float tile[64][65];
  const float* in; u16* out; int C, blk;
  blk = bx - 4096;
  if (blk < 768) { in = Wp; out = WpT; C = 3072; }
  else           { in = Wo; out = WoT; C = 1024; blk -= 768; }
  const int R = 1024;
  int nbc = C >> 6;
  int c0 = (blk % nbc) << 6;
  int r0 = (blk / nbc) << 6;
  int li = t & 15;
  int hi = t >> 4;  // 0..15
  for (int i = 0; i < 4; i++) {
    int r = hi + (i << 4);
    float4 v = *(const float4*)&in[(size_t)(r0 + r) * C + c0 + (li << 2)];
    tile[r][(li << 2) + 0] = v.x;
    tile[r][(li << 2) + 1] = v.y;
    tile[r][(li << 2) + 2] = v.z;
    tile[r][(li << 2) + 3] = v.w;
  }
  __syncthreads();
  int rr4 = li << 2;
  for (int i = 0; i < 4; i++) {
    int col = hi + (i << 4);
    ushort4 o;
    o.x = f2bf(tile[rr4 + 0][col]);
    o.y = f2bf(tile[rr4 + 1][col]);
    o.z = f2bf(tile[rr4 + 2][col]);
    o.w = f2bf(tile[rr4 + 3][col]);
    *(ushort4*)&out[(size_t)(c0 + col) * R + r0 + rr4] = o;
  }
}

// ---------------- fused QKV projection GEMM: A direct-from-global, B via LDS -----
// A = x_bf [4096,1024], Bt = WpT [3072,1024]. Grid (48,32), BM=128 BN=64 BK=64.
// A-fragments are contiguous 16B/lane in global (row=l15, k=quad*8) -> loaded
// straight from L2 (A slab reused by 48 n-blocks). Only B staged in LDS (8 KB).
// A loads issued alongside B DMA so one barrier drain covers both latencies.
__global__ __launch_bounds__(256, 2) void gemm_qkv(
    const u16* __restrict__ A, const u16* __restrict__ Bt,
    const float* __restrict__ bias, u16* __restrict__ qkb, u16* __restrict__ Vtb) {
  __shared__ __align__(16) u16 Bs[4096];  // [half][64][32]
  int t = threadIdx.x;
  int w = t >> 6, lane = t & 63, quad = lane >> 4, l15 = lane & 15;
  int wr = w >> 1, wc = w & 1;
  int m0 = blockIdx.y * 128;
  int n0 = blockIdx.x * 64;
  bool isqk = (n0 < 2048);

  const u16* gB[2]; u16* lB[2];
  {
    int rbase = t >> 2, cg = t & 3;
    for (int i = 0; i < 2; i++) {
      gB[i] = Bt + (size_t)(n0 + rbase) * 1024 + i * 32 + cg * 8;
      lB[i] = &Bs[i * 2048 + rbase * 32 + cg * 8];
    }
  }
  // per-lane A fragment base: row m0 + wr*64 + l15, col quad*8
  const u16* aA = A + (size_t)(m0 + wr * 64 + l15) * 1024 + quad * 8;

  f32x4 acc[4][2];
  f32x4 zero = {0.f, 0.f, 0.f, 0.f};
  for (int mt = 0; mt < 4; mt++)
    for (int nt = 0; nt < 2; nt++) acc[mt][nt] = zero;

  for (int k0 = 0; k0 < 1024; k0 += 64) {
    __syncthreads();  // all waves done reading Bs
    async_cp16(gB[0] + k0, lB[0]);
    async_cp16(gB[1] + k0, lB[1]);
    short8 af[2][4];
    for (int kc = 0; kc < 2; kc++)
      for (int mt = 0; mt < 4; mt++)
        af[kc][mt] = *(const short8*)&aA[k0 + kc * 32 + (size_t)mt * 16 * 1024];
    __syncthreads();  // drains B DMA and A loads together
    for (int kc = 0; kc < 2; kc++) {
      short8 bf[2];
      for (int nt = 0; nt < 2; nt++)
        bf[nt] = *(const short8*)&Bs[kc * 2048 + (wc * 32 + nt * 16 + l15) * 32 + quad * 8];
      if (isqk) {
        for (int mt = 0; mt < 4; mt++)
          for (int nt = 0; nt < 2; nt++)
            acc[mt][nt] = MFMA16(bf[nt], af[kc][mt], acc[mt][nt]);  // D[n][m]
      } else {
        for (int mt = 0; mt < 4; mt++)
          for (int nt = 0; nt < 2; nt++)
            acc[mt][nt] = MFMA16(af[kc][mt], bf[nt], acc[mt][nt]);  // D[m][n]
      }
    }
  }
  if (isqk) {
    // Q columns get the softmax pre-scale folded in (K columns do not).
    float qscale = (n0 < 1024) ? 0.18033688011112042f : 1.0f;  // 0.125*log2(e)
    for (int mt = 0; mt < 4; mt++) {
      int m = m0 + wr * 64 + mt * 16 + l15;
      for (int nt = 0; nt < 2; nt++) {
        int nb = n0 + wc * 32 + nt * 16 + quad * 4;
        float4 bv = *(const float4*)&bias[nb];
        ushort4 o;
        o.x = f2bf((acc[mt][nt][0] + bv.x) * qscale);
        o.y = f2bf((acc[mt][nt][1] + bv.y) * qscale);
        o.z = f2bf((acc[mt][nt][2] + bv.z) * qscale);
        o.w = f2bf((acc[mt][nt][3] + bv.w) * qscale);
        *(ushort4*)&qkb[(size_t)m * 2048 + nb] = o;
      }
    }
  } else {
    for (int nt = 0; nt < 2; nt++) {
      int n = n0 + wc * 32 + nt * 16 + l15;
      float bv = bias[n];
      int d = n - 2048;
      for (int mt = 0; mt < 4; mt++) {
        int mb = m0 + wr * 64 + mt * 16 + quad * 4;
        ushort4 o;
        o.x = f2bf(acc[mt][nt][0] + bv);
        o.y = f2bf(acc[mt][nt][1] + bv);
        o.z = f2bf(acc[mt][nt][2] + bv);
        o.w = f2bf(acc[mt][nt][3] + bv);
        *(ushort4*)&Vtb[(size_t)d * 4096 + mb] = o;
      }
    }
  }
}

// ---------------- output projection GEMM: A direct-from-global, B via LDS --------
// A = y [4096,1024], Bt = WoT [1024,1024]. D[n][m]: float4 X loads + Z stores.
__global__ __launch_bounds__(256, 2) void gemm_out_res(
    const u16* __restrict__ A, const u16* __restrict__ Bt,
    const float* __restrict__ bias, const float* __restrict__ X,
    float* __restrict__ Z) {
  __shared__ __align__(16) u16 Bs[4096];  // [half][64][32]
  int t = threadIdx.x;
  int w = t >> 6, lane = t & 63, quad = lane >> 4, l15 = lane & 15;
  int wr = w >> 1, wc = w & 1;
  int m0 = blockIdx.y * 128;
  int n0 = blockIdx.x * 64;

  const u16* gB[2]; u16* lB[2];
  {
    int rbase = t >> 2, cg = t & 3;
    for (int i = 0; i < 2; i++) {
      gB[i] = Bt + (size_t)(n0 + rbase) * 1024 + i * 32 + cg * 8;
      lB[i] = &Bs[i * 2048 + rbase * 32 + cg * 8];
    }
  }
  const u16* aA = A + (size_t)(m0 + wr * 64 + l15) * 1024 + quad * 8;

  f32x4 acc[4][2];
  f32x4 zero = {0.f, 0.f, 0.f, 0.f};
  for (int mt = 0; mt < 4; mt++)
    for (int nt = 0; nt < 2; nt++) acc[mt][nt] = zero;

  for (int k0 = 0; k0 < 1024; k0 += 64) {
    __syncthreads();
    async_cp16(gB[0] + k0, lB[0]);
    async_cp16(gB[1] + k0, lB[1]);
    short8 af[2][4];
    for (int kc = 0; kc < 2; kc++)
      for (int mt = 0; mt < 4; mt++)
        af[kc][mt] = *(const short8*)&aA[k0 + kc * 32 + (size_t)mt * 16 * 1024];
    __syncthreads();
    for (int kc = 0; kc < 2; kc++) {
      short8 bf[2];
      for (int nt = 0; nt < 2; nt++)
        bf[nt] = *(const short8*)&Bs[kc * 2048 + (wc * 32 + nt * 16 + l15) * 32 + quad * 8];
      for (int mt = 0; mt < 4; mt++)
        for (int nt = 0; nt < 2; nt++)
          acc[mt][nt] = MFMA16(bf[nt], af[kc][mt], acc[mt][nt]);  // D[n][m]
    }
  }
  for (int mt = 0; mt < 4; mt++) {
    int m = m0 + wr * 64 + mt * 16 + l15;
    for (int nt = 0; nt < 2; nt++) {
      int nb = n0 + wc * 32 + nt * 16 + quad * 4;
      float4 bv = *(const float4*)&bias[nb];
      size_t idx = (size_t)m * 1024 + nb;
      float4 xv = *(const float4*)&X[idx];
      float4 o;
      o.x = acc[mt][nt][0] + bv.x + xv.x;
      o.y = acc[mt][nt][1] + bv.y + xv.y;
      o.z = acc[mt][nt][2] + bv.z + xv.z;
      o.w = acc[mt][nt][3] + bv.w + xv.w;
      *(float4*)&Z[idx] = o;
    }
  }
}

// ---------------- Flash-style causal attention v5: transposed-S softmax ----------
#define LDPK 72
__global__ __launch_bounds__(256, 2) void attn_v5(
    const u16* __restrict__ qk, const u16* __restrict__ Vt,
    u16* __restrict__ y) {
  __shared__ __align__(16) u16 K_lds[2][4096];
  __shared__ __align__(16) u16 V_lds[2][4096];
  __shared__ __align__(16) u16 P_lds[4 * 16 * LDPK];
  __shared__ float rs_sh[4][16];
  int bx = blockIdx.x;
  int sub = bx >> 3;
  int bh = (bx & 7) * 4 + (sub >> 4);  // all 16 slots of bh share bx%8
  int slot = sub & 15;
  int h = bh & 15, b = bh >> 4;
  int t = threadIdx.x, w = t >> 6, lane = t & 63, quad = lane >> 4, l15 = lane & 15;
  size_t rowbase = (size_t)b * 2048;
  u16* Pw = P_lds + w * 16 * LDPK;
  f32x4 zero = {0.f, 0.f, 0.f, 0.f};

  const u16 *Kg[2], *Vg[2];
  u16 *Kl[2][2], *Vl[2][2];
  for (int i = 0; i < 2; i++) {
    int c = t + 256 * i;
    int half = c >> 8, row = (c >> 2) & 63, cg = c & 3;
    int col = half * 32 + cg * 8;
    Kg[i] = qk + (rowbase + row) * 2048 + 1024 + h * 64 + col;   // + kt*64*2048
    Vg[i] = Vt + (size_t)(h * 64 + row) * 4096 + rowbase + col;  // + kt*64
    Kl[0][i] = &K_lds[0][c * 8]; Kl[1][i] = &K_lds[1][c * 8];
    Vl[0][i] = &V_lds[0][c * 8]; Vl[1][i] = &V_lds[1][c * 8];
  }

  for (int i = 0; i < 2; i++) { async_cp16(Kg[i], Kl[0][i]); async_cp16(Vg[i], Vl[0][i]); }

  int cur = 0;
  for (int pass = 0; pass < 2; pass++) {
    int qt = pass ? (31 - slot) : slot;
    int q0 = qt * 64;
    short8 qf0, qf1;
    {
      const u16* qp = qk + (rowbase + q0 + w * 16 + l15) * 2048 + h * 64 + quad * 8;
      qf0 = *(const short8*)qp;
      qf1 = *(const short8*)(qp + 32);
    }
    f32x4 o[4];
    for (int nt = 0; nt < 4; nt++) o[nt] = zero;
    float rsl = 0.f;  // lane-local partial row sum for q = l15 (this wave)

    for (int kt = 0; kt <= qt; kt++) {
      __syncthreads();  // tile kt ready in buf cur; all waves done with buf cur^1
      int nxt = cur ^ 1;
      if (kt < qt) {
        size_t ko = (size_t)(kt + 1) * 64;
        for (int i = 0; i < 2; i++) {
          async_cp16(Kg[i] + ko * 2048, Kl[nxt][i]);
          async_cp16(Vg[i] + ko, Vl[nxt][i]);
        }
      } else if (pass == 0) {
        for (int i = 0; i < 2; i++) { async_cp16(Kg[i], Kl[nxt][i]); async_cp16(Vg[i], Vl[nxt][i]); }
      }
      const u16* Kb = K_lds[cur];
      const u16* Vb = V_lds[cur];
      // St = K.Q^T : St[k=nt*16+quad*4+r][q=l15] per nt sub-tile
      f32x4 s[4];
      for (int nt = 0; nt < 4; nt++) {
        const u16* kr = Kb + (nt * 16 + l15) * 32 + quad * 8;
        f32x4 a2 = zero;
        a2 = MFMA16(*(const short8*)kr, qf0, a2);
        a2 = MFMA16(*(const short8*)(kr + 2048), qf1, a2);
        s[nt] = a2;
      }
      bool diag = (kt == qt);
      int qg = w * 16 + l15;            // q local to block
      for (int nt = 0; nt < 4; nt++) {
        int kl = nt * 16 + quad * 4;    // k local to tile
        float p0 = fast_exp2(s[nt][0]);
        float p1 = fast_exp2(s[nt][1]);
        float p2 = fast_exp2(s[nt][2]);
        float p3 = fast_exp2(s[nt][3]);
        if (diag) {
          if (kl + 0 > qg) p0 = 0.f;
          if (kl + 1 > qg) p1 = 0.f;
          if (kl + 2 > qg) p2 = 0.f;
          if (kl + 3 > qg) p3 = 0.f;
        }
        rsl += (p0 + p1) + (p2 + p3);
        uint32_t w0 = __builtin_amdgcn_perm(__float_as_uint(p1), __float_as_uint(p0), 0x07060302u);
        uint32_t w1 = __builtin_amdgcn_perm(__float_as_uint(p3), __float_as_uint(p2), 0x07060302u);
        uint2 pk; pk.x = w0; pk.y = w1;
        *(uint2*)&Pw[l15 * LDPK + kl] = pk;
      }
      for (int c2 = 0; c2 < 2; c2++) {
        short8 af = *(const short8*)&Pw[l15 * LDPK + c2 * 32 + quad * 8];
        for (int nt = 0; nt < 4; nt++) {
          const short8 bv = *(const short8*)&Vb[c2 * 2048 + (nt * 16 + l15) * 32 + quad * 8];
          o[nt] = MFMA16(af, bv, o[nt]);
        }
      }
      cur = nxt;
    }
    rsl += __shfl_xor(rsl, 16, 64);
    rsl += __shfl_xor(rsl, 32, 64);
    if (lane < 16) rs_sh[w][lane] = rsl;
    float rq[4];
    for (int r = 0; r < 4; r++) rq[r] = rs_sh[w][quad * 4 + r] + 1e-9f;
    for (int nt = 0; nt < 4; nt++) {
      for (int r = 0; r < 4; r++) {
        float ov = o[nt][r] / rq[r];
        size_t qr = rowbase + q0 + w * 16 + quad * 4 + r;
        y[qr * 1024 + h * 64 + nt * 16 + l15] = f2bf(ov);
      }
    }
  }
}

// ---------------- LayerNorm over D=1024, one block per row ----------------
__global__ __launch_bounds__(256) void ln_kernel(const float* __restrict__ Z,
                                                 const float* __restrict__ gamma,
                                                 const float* __restrict__ beta,
                                                 float* __restrict__ out) {
  int row = blockIdx.x;
  int t = threadIdx.x;
  float4 v = ((const float4*)(Z + (size_t)row * 1024))[t];
  float s = v.x + v.y + v.z + v.w;
  float s2 = v.x * v.x + v.y * v.y + v.z * v.z + v.w * v.w;
  for (int m = 1; m < 64; m <<= 1) {
    s += __shfl_xor(s, m, 64);
    s2 += __shfl_xor(s2, m, 64);
  }
  __shared__ float ss[4], ss2[4];
  int w = t >> 6;
  if ((t & 63) == 0) { ss[w] = s; ss2[w] = s2; }
  __syncthreads();
  s = ss[0] + ss[1] + ss[2] + ss[3];
  s2 = ss2[0] + ss2[1] + ss2[2] + ss2[3];
  float mu = s * (1.0f / 1024.0f);
  float var = s2 * (1.0f / 1024.0f) - mu * mu;
  float inv = rsqrtf(var + 1e-5f);
  float4 g = ((const float4*)gamma)[t];
  float4 bb = ((const float4*)beta)[t];
  float4 o;
  o.x = (v.x - mu) * inv * g.x + bb.x;
  o.y = (v.y - mu) * inv * g.y + bb.y;
  o.z = (v.z - mu) * inv * g.z + bb.z;
  o.w = (v.w - mu) * inv * g.w + bb.w;
  ((float4*)(out + (size_t)row * 1024))[t] = o;
}

extern "C" void kernel_launch(void* const* d_in, const int* in_sizes, int n_in,
                              void* d_out, int out_size, void* d_ws, size_t ws_size,
                              hipStream_t stream) {
  const float* x     = (const float*)d_in[0];
  // d_in[1] = attn_mask: causal by construction; synthesized in-kernel.
  const float* Wp    = (const float*)d_in[2];
  const float* bp    = (const float*)d_in[3];
  const float* Wo    = (const float*)d_in[4];
  const float* bo    = (const float*)d_in[5];
  const float* gamma = (const float*)d_in[6];
  const float* beta  = (const float*)d_in[7];
  float* out = (float*)d_out;

  char* ws = (char*)d_ws;
  u16*   x_bf = (u16*)(ws);                    //  8 MB: [4096,1024] bf16
  u16*   WpT  = (u16*)(ws + 8388608);          //  6 MB: [3072,1024] bf16
  u16*   WoT  = (u16*)(ws + 14680064);         //  2 MB: [1024,1024] bf16
  u16*   qkb  = (u16*)(ws + 16777216);         // 16 MB: [4096,2048] bf16 (Q|K)
  u16*   Vtb  = (u16*)(ws + 33554432);         //  8 MB: [1024,4096] bf16 (V^T)
  u16*   y    = (u16*)(ws + 41943040);         //  8 MB: [4096,1024] bf16
  float* z    = (float*)(ws + 50331648);       // 16 MB: [4096,1024] fp32

  prep<<<5120, 256, 0, stream>>>(x, Wp, Wo, x_bf, WpT, WoT);

  dim3 gqkv(48, 32);
  gemm_qkv<<<gqkv, 256, 0, stream>>>(x_bf, WpT, bp, qkb, Vtb);

  attn_v5<<<512, 256, 0, stream>>>(qkb, Vtb, y);

  dim3 go(16, 32);
  gemm_out_res<<<go, 256, 0, stream>>>(y, WoT, bo, x, z);

  ln_kernel<<<4096, 256, 0, stream>>>(z, gamma, beta, out);
}

// Round 10
// 209.409 us; speedup vs baseline: 1.3747x; 1.3747x over previous
//
#include <hip/hip_runtime.h>
#include <stdint.h>

typedef unsigned short u16;
typedef __attribute__((ext_vector_type(8))) short short8;
typedef __attribute__((ext_vector_type(4))) short sh4;
typedef __attribute__((ext_vector_type(4))) float f32x4;

#define MFMA16(a,b,c) __builtin_amdgcn_mfma_f32_16x16x32_bf16((a),(b),(c),0,0,0)

__device__ __forceinline__ u16 f2bf(float f) {
  union { float f; uint32_t u; } c; c.f = f;
  uint32_t u = c.u;
  return (u16)((u + 0x7fffu + ((u >> 16) & 1u)) >> 16);
}

__device__ __forceinline__ float fast_exp2(float x) {
#if __has_builtin(__builtin_amdgcn_exp2f)
  return __builtin_amdgcn_exp2f(x);
#else
  return __expf(x * 0.69314718056f);
#endif
}

// async global->LDS, 16B per lane; LDS dest = wave-uniform base + lane*16
__device__ __forceinline__ void async_cp16(const void* g, void* l) {
  __builtin_amdgcn_global_load_lds((__attribute__((address_space(1))) void*)g,
                                   (__attribute__((address_space(3))) void*)l,
                                   16, 0, 0);
}

// ---------------- fused prep: cvt x -> bf16; transpose Wp, Wo (64x64 tiles) ------
__global__ __launch_bounds__(256) void prep(const float* __restrict__ x,
                                            const float* __restrict__ Wp,
                                            const float* __restrict__ Wo,
                                            u16* __restrict__ x_bf,
                                            u16* __restrict__ WpT,
                                            u16* __restrict__ WoT) {
  int bx = blockIdx.x;
  int t = threadIdx.x;
  if (bx < 4096) {
    int i = bx * 256 + t;
    float4 v = ((const float4*)x)[i];
    ushort4 o; o.x = f2bf(v.x); o.y = f2bf(v.y); o.z = f2bf(v.z); o.w = f2bf(v.w);
    ((ushort4*)x_bf)[i] = o;
    return;
  }
  __shared__ float tile[64][65];
  const float* in; u16* out; int C, blk;
  blk = bx - 4096;
  if (blk < 768) { in = Wp; out = WpT; C = 3072; }
  else           { in = Wo; out = WoT; C = 1024; blk -= 768; }
  const int R = 1024;
  int nbc = C >> 6;
  int c0 = (blk % nbc) << 6;
  int r0 = (blk / nbc) << 6;
  int li = t & 15;
  int hi = t >> 4;  // 0..15
  for (int i = 0; i < 4; i++) {
    int r = hi + (i << 4);
    float4 v = *(const float4*)&in[(size_t)(r0 + r) * C + c0 + (li << 2)];
    tile[r][(li << 2) + 0] = v.x;
    tile[r][(li << 2) + 1] = v.y;
    tile[r][(li << 2) + 2] = v.z;
    tile[r][(li << 2) + 3] = v.w;
  }
  __syncthreads();
  int rr4 = li << 2;
  for (int i = 0; i < 4; i++) {
    int col = hi + (i << 4);
    ushort4 o;
    o.x = f2bf(tile[rr4 + 0][col]);
    o.y = f2bf(tile[rr4 + 1][col]);
    o.z = f2bf(tile[rr4 + 2][col]);
    o.w = f2bf(tile[rr4 + 3][col]);
    *(ushort4*)&out[(size_t)(c0 + col) * R + r0 + rr4] = o;
  }
}

// ---------------- fused QKV projection GEMM, BM=128 BN=64 BK=64 (R8 config) ------
__global__ __launch_bounds__(256, 2) void gemm_qkv(
    const u16* __restrict__ A, const u16* __restrict__ Bt,
    const float* __restrict__ bias, u16* __restrict__ qkb, u16* __restrict__ Vtb) {
  __shared__ __align__(16) u16 As[8192];  // [half][128][32]
  __shared__ __align__(16) u16 Bs[4096];  // [half][64][32]
  int t = threadIdx.x;
  int w = t >> 6, lane = t & 63, quad = lane >> 4, l15 = lane & 15;
  int wr = w >> 1, wc = w & 1;
  int m0 = blockIdx.y * 128;
  int n0 = blockIdx.x * 64;
  bool isqk = (n0 < 2048);

  const u16* gA[4]; u16* lA[4];
  const u16* gB[2]; u16* lB[2];
  {
    int rbase = t >> 2, cg = t & 3;
    for (int i = 0; i < 4; i++) {
      int r = rbase + (i & 1) * 64;
      int half = i >> 1;
      gA[i] = A + (size_t)(m0 + r) * 1024 + half * 32 + cg * 8;
      lA[i] = &As[half * 4096 + r * 32 + cg * 8];
    }
    for (int i = 0; i < 2; i++) {
      gB[i] = Bt + (size_t)(n0 + rbase) * 1024 + i * 32 + cg * 8;
      lB[i] = &Bs[i * 2048 + rbase * 32 + cg * 8];
    }
  }

  f32x4 acc[4][2];
  f32x4 zero = {0.f, 0.f, 0.f, 0.f};
  for (int mt = 0; mt < 4; mt++)
    for (int nt = 0; nt < 2; nt++) acc[mt][nt] = zero;

  for (int k0 = 0; k0 < 1024; k0 += 64) {
    __syncthreads();
    for (int i = 0; i < 4; i++) async_cp16(gA[i] + k0, lA[i]);
    for (int i = 0; i < 2; i++) async_cp16(gB[i] + k0, lB[i]);
    __syncthreads();
    for (int kc = 0; kc < 2; kc++) {
      short8 af[4], bf[2];
      for (int mt = 0; mt < 4; mt++)
        af[mt] = *(const short8*)&As[kc * 4096 + (wr * 64 + mt * 16 + l15) * 32 + quad * 8];
      for (int nt = 0; nt < 2; nt++)
        bf[nt] = *(const short8*)&Bs[kc * 2048 + (wc * 32 + nt * 16 + l15) * 32 + quad * 8];
      if (isqk) {
        for (int mt = 0; mt < 4; mt++)
          for (int nt = 0; nt < 2; nt++)
            acc[mt][nt] = MFMA16(bf[nt], af[mt], acc[mt][nt]);  // D[n][m]
      } else {
        for (int mt = 0; mt < 4; mt++)
          for (int nt = 0; nt < 2; nt++)
            acc[mt][nt] = MFMA16(af[mt], bf[nt], acc[mt][nt]);  // D[m][n]
      }
    }
  }
  if (isqk) {
    float qscale = (n0 < 1024) ? 0.18033688011112042f : 1.0f;  // 0.125*log2(e)
    for (int mt = 0; mt < 4; mt++) {
      int m = m0 + wr * 64 + mt * 16 + l15;
      for (int nt = 0; nt < 2; nt++) {
        int nb = n0 + wc * 32 + nt * 16 + quad * 4;
        float4 bv = *(const float4*)&bias[nb];
        ushort4 o;
        o.x = f2bf((acc[mt][nt][0] + bv.x) * qscale);
        o.y = f2bf((acc[mt][nt][1] + bv.y) * qscale);
        o.z = f2bf((acc[mt][nt][2] + bv.z) * qscale);
        o.w = f2bf((acc[mt][nt][3] + bv.w) * qscale);
        *(ushort4*)&qkb[(size_t)m * 2048 + nb] = o;
      }
    }
  } else {
    for (int nt = 0; nt < 2; nt++) {
      int n = n0 + wc * 32 + nt * 16 + l15;
      float bv = bias[n];
      int d = n - 2048;
      for (int mt = 0; mt < 4; mt++) {
        int mb = m0 + wr * 64 + mt * 16 + quad * 4;
        ushort4 o;
        o.x = f2bf(acc[mt][nt][0] + bv);
        o.y = f2bf(acc[mt][nt][1] + bv);
        o.z = f2bf(acc[mt][nt][2] + bv);
        o.w = f2bf(acc[mt][nt][3] + bv);
        *(ushort4*)&Vtb[(size_t)d * 4096 + mb] = o;
      }
    }
  }
}

// ---------------- output projection GEMM, BM=128 BN=64 BK=64 (R8 config) ---------
__global__ __launch_bounds__(256, 2) void gemm_out_res(
    const u16* __restrict__ A, const u16* __restrict__ Bt,
    const float* __restrict__ bias, const float* __restrict__ X,
    float* __restrict__ Z) {
  __shared__ __align__(16) u16 As[8192];  // [half][128][32]
  __shared__ __align__(16) u16 Bs[4096];  // [half][64][32]
  int t = threadIdx.x;
  int w = t >> 6, lane = t & 63, quad = lane >> 4, l15 = lane & 15;
  int wr = w >> 1, wc = w & 1;
  int m0 = blockIdx.y * 128;
  int n0 = blockIdx.x * 64;

  const u16* gA[4]; u16* lA[4];
  const u16* gB[2]; u16* lB[2];
  {
    int rbase = t >> 2, cg = t & 3;
    for (int i = 0; i < 4; i++) {
      int r = rbase + (i & 1) * 64;
      int half = i >> 1;
      gA[i] = A + (size_t)(m0 + r) * 1024 + half * 32 + cg * 8;
      lA[i] = &As[half * 4096 + r * 32 + cg * 8];
    }
    for (int i = 0; i < 2; i++) {
      gB[i] = Bt + (size_t)(n0 + rbase) * 1024 + i * 32 + cg * 8;
      lB[i] = &Bs[i * 2048 + rbase * 32 + cg * 8];
    }
  }

  f32x4 acc[4][2];
  f32x4 zero = {0.f, 0.f, 0.f, 0.f};
  for (int mt = 0; mt < 4; mt++)
    for (int nt = 0; nt < 2; nt++) acc[mt][nt] = zero;

  for (int k0 = 0; k0 < 1024; k0 += 64) {
    __syncthreads();
    for (int i = 0; i < 4; i++) async_cp16(gA[i] + k0, lA[i]);
    for (int i = 0; i < 2; i++) async_cp16(gB[i] + k0, lB[i]);
    __syncthreads();
    for (int kc = 0; kc < 2; kc++) {
      short8 af[4], bf[2];
      for (int mt = 0; mt < 4; mt++)
        af[mt] = *(const short8*)&As[kc * 4096 + (wr * 64 + mt * 16 + l15) * 32 + quad * 8];
      for (int nt = 0; nt < 2; nt++)
        bf[nt] = *(const short8*)&Bs[kc * 2048 + (wc * 32 + nt * 16 + l15) * 32 + quad * 8];
      for (int mt = 0; mt < 4; mt++)
        for (int nt = 0; nt < 2; nt++)
          acc[mt][nt] = MFMA16(bf[nt], af[mt], acc[mt][nt]);  // D[n][m]
    }
  }
  for (int mt = 0; mt < 4; mt++) {
    int m = m0 + wr * 64 + mt * 16 + l15;
    for (int nt = 0; nt < 2; nt++) {
      int nb = n0 + wc * 32 + nt * 16 + quad * 4;
      float4 bv = *(const float4*)&bias[nb];
      size_t idx = (size_t)m * 1024 + nb;
      float4 xv = *(const float4*)&X[idx];
      float4 o;
      o.x = acc[mt][nt][0] + bv.x + xv.x;
      o.y = acc[mt][nt][1] + bv.y + xv.y;
      o.z = acc[mt][nt][2] + bv.z + xv.z;
      o.w = acc[mt][nt][3] + bv.w + xv.w;
      *(float4*)&Z[idx] = o;
    }
  }
}

// ---------------- Flash-style causal attention v6 --------------------------------
// One q-tile per block: 1024 blocks = 4/CU. Descending-qt dispatch (long blocks
// first). XCD: all 32 q-tiles of a bh land on XCD bh%8 (stride 32 ≡ 0 mod 8).
// Inner loop identical to v5 (dbuf async staging, transposed-S softmax).
#define LDPK 72
__global__ __launch_bounds__(256, 2) void attn_v6(
    const u16* __restrict__ qk, const u16* __restrict__ Vt,
    u16* __restrict__ y) {
  __shared__ __align__(16) u16 K_lds[2][4096];
  __shared__ __align__(16) u16 V_lds[2][4096];
  __shared__ __align__(16) u16 P_lds[4 * 16 * LDPK];
  __shared__ float rs_sh[4][16];
  int bx = blockIdx.x;
  int bh = bx & 31;             // K/V of bh live on XCD bh%8
  int qt = 31 - (bx >> 5);      // large q-tiles dispatch first
  int h = bh & 15, b = bh >> 4;
  int t = threadIdx.x, w = t >> 6, lane = t & 63, quad = lane >> 4, l15 = lane & 15;
  size_t rowbase = (size_t)b * 2048;
  u16* Pw = P_lds + w * 16 * LDPK;
  f32x4 zero = {0.f, 0.f, 0.f, 0.f};

  const u16 *Kg[2], *Vg[2];
  u16 *Kl[2][2], *Vl[2][2];
  for (int i = 0; i < 2; i++) {
    int c = t + 256 * i;
    int half = c >> 8, row = (c >> 2) & 63, cg = c & 3;
    int col = half * 32 + cg * 8;
    Kg[i] = qk + (rowbase + row) * 2048 + 1024 + h * 64 + col;   // + kt*64*2048
    Vg[i] = Vt + (size_t)(h * 64 + row) * 4096 + rowbase + col;  // + kt*64
    Kl[0][i] = &K_lds[0][c * 8]; Kl[1][i] = &K_lds[1][c * 8];
    Vl[0][i] = &V_lds[0][c * 8]; Vl[1][i] = &V_lds[1][c * 8];
  }

  for (int i = 0; i < 2; i++) { async_cp16(Kg[i], Kl[0][i]); async_cp16(Vg[i], Vl[0][i]); }

  int cur = 0;
  int q0 = qt * 64;
  short8 qf0, qf1;
  {
    const u16* qp = qk + (rowbase + q0 + w * 16 + l15) * 2048 + h * 64 + quad * 8;
    qf0 = *(const short8*)qp;
    qf1 = *(const short8*)(qp + 32);
  }
  f32x4 o[4];
  for (int nt = 0; nt < 4; nt++) o[nt] = zero;
  float rsl = 0.f;  // lane-local partial row sum for q = l15 (this wave)

  for (int kt = 0; kt <= qt; kt++) {
    __syncthreads();  // tile kt ready in buf cur; all waves done with buf cur^1
    int nxt = cur ^ 1;
    if (kt < qt) {
      size_t ko = (size_t)(kt + 1) * 64;
      for (int i = 0; i < 2; i++) {
        async_cp16(Kg[i] + ko * 2048, Kl[nxt][i]);
        async_cp16(Vg[i] + ko, Vl[nxt][i]);
      }
    }
    const u16* Kb = K_lds[cur];
    const u16* Vb = V_lds[cur];
    // St = K.Q^T : St[k=nt*16+quad*4+r][q=l15] per nt sub-tile
    f32x4 s[4];
    for (int nt = 0; nt < 4; nt++) {
      const u16* kr = Kb + (nt * 16 + l15) * 32 + quad * 8;
      f32x4 a2 = zero;
      a2 = MFMA16(*(const short8*)kr, qf0, a2);
      a2 = MFMA16(*(const short8*)(kr + 2048), qf1, a2);
      s[nt] = a2;
    }
    bool diag = (kt == qt);
    int qg = w * 16 + l15;            // q local to block
    for (int nt = 0; nt < 4; nt++) {
      int kl = nt * 16 + quad * 4;    // k local to tile
      float p0 = fast_exp2(s[nt][0]);
      float p1 = fast_exp2(s[nt][1]);
      float p2 = fast_exp2(s[nt][2]);
      float p3 = fast_exp2(s[nt][3]);
      if (diag) {
        if (kl + 0 > qg) p0 = 0.f;
        if (kl + 1 > qg) p1 = 0.f;
        if (kl + 2 > qg) p2 = 0.f;
        if (kl + 3 > qg) p3 = 0.f;
      }
      rsl += (p0 + p1) + (p2 + p3);
      uint32_t w0 = __builtin_amdgcn_perm(__float_as_uint(p1), __float_as_uint(p0), 0x07060302u);
      uint32_t w1 = __builtin_amdgcn_perm(__float_as_uint(p3), __float_as_uint(p2), 0x07060302u);
      uint2 pk; pk.x = w0; pk.y = w1;
      *(uint2*)&Pw[l15 * LDPK + kl] = pk;
    }
    for (int c2 = 0; c2 < 2; c2++) {
      short8 af = *(const short8*)&Pw[l15 * LDPK + c2 * 32 + quad * 8];
      for (int nt = 0; nt < 4; nt++) {
        const short8 bv = *(const short8*)&Vb[c2 * 2048 + (nt * 16 + l15) * 32 + quad * 8];
        o[nt] = MFMA16(af, bv, o[nt]);
      }
    }
    cur = nxt;
  }
  rsl += __shfl_xor(rsl, 16, 64);
  rsl += __shfl_xor(rsl, 32, 64);
  if (lane < 16) rs_sh[w][lane] = rsl;
  float rq[4];
  for (int r = 0; r < 4; r++) rq[r] = rs_sh[w][quad * 4 + r] + 1e-9f;
  for (int nt = 0; nt < 4; nt++) {
    for (int r = 0; r < 4; r++) {
      float ov = o[nt][r] / rq[r];
      size_t qr = rowbase + q0 + w * 16 + quad * 4 + r;
      y[qr * 1024 + h * 64 + nt * 16 + l15] = f2bf(ov);
    }
  }
}

// ---------------- LayerNorm over D=1024, one block per row ----------------
__global__ __launch_bounds__(256) void ln_kernel(const float* __restrict__ Z,
                                                 const float* __restrict__ gamma,
                                                 const float* __restrict__ beta,
                                                 float* __restrict__ out) {
  int row = blockIdx.x;
  int t = threadIdx.x;
  float4 v = ((const float4*)(Z + (size_t)row * 1024))[t];
  float s = v.x + v.y + v.z + v.w;
  float s2 = v.x * v.x + v.y * v.y + v.z * v.z + v.w * v.w;
  for (int m = 1; m < 64; m <<= 1) {
    s += __shfl_xor(s, m, 64);
    s2 += __shfl_xor(s2, m, 64);
  }
  __shared__ float ss[4], ss2[4];
  int w = t >> 6;
  if ((t & 63) == 0) { ss[w] = s; ss2[w] = s2; }
  __syncthreads();
  s = ss[0] + ss[1] + ss[2] + ss[3];
  s2 = ss2[0] + ss2[1] + ss2[2] + ss2[3];
  float mu = s * (1.0f / 1024.0f);
  float var = s2 * (1.0f / 1024.0f) - mu * mu;
  float inv = rsqrtf(var + 1e-5f);
  float4 g = ((const float4*)gamma)[t];
  float4 bb = ((const float4*)beta)[t];
  float4 o;
  o.x = (v.x - mu) * inv * g.x + bb.x;
  o.y = (v.y - mu) * inv * g.y + bb.y;
  o.z = (v.z - mu) * inv * g.z + bb.z;
  o.w = (v.w - mu) * inv * g.w + bb.w;
  ((float4*)(out + (size_t)row * 1024))[t] = o;
}

extern "C" void kernel_launch(void* const* d_in, const int* in_sizes, int n_in,
                              void* d_out, int out_size, void* d_ws, size_t ws_size,
                              hipStream_t stream) {
  const float* x     = (const float*)d_in[0];
  // d_in[1] = attn_mask: causal by construction; synthesized in-kernel.
  const float* Wp    = (const float*)d_in[2];
  const float* bp    = (const float*)d_in[3];
  const float* Wo    = (const float*)d_in[4];
  const float* bo    = (const float*)d_in[5];
  const float* gamma = (const float*)d_in[6];
  const float* beta  = (const float*)d_in[7];
  float* out = (float*)d_out;

  char* ws = (char*)d_ws;
  u16*   x_bf = (u16*)(ws);                    //  8 MB: [4096,1024] bf16
  u16*   WpT  = (u16*)(ws + 8388608);          //  6 MB: [3072,1024] bf16
  u16*   WoT  = (u16*)(ws + 14680064);         //  2 MB: [1024,1024] bf16
  u16*   qkb  = (u16*)(ws + 16777216);         // 16 MB: [4096,2048] bf16 (Q|K)
  u16*   Vtb  = (u16*)(ws + 33554432);         //  8 MB: [1024,4096] bf16 (V^T)
  u16*   y    = (u16*)(ws + 41943040);         //  8 MB: [4096,1024] bf16
  float* z    = (float*)(ws + 50331648);       // 16 MB: [4096,1024] fp32

  prep<<<5120, 256, 0, stream>>>(x, Wp, Wo, x_bf, WpT, WoT);

  dim3 gqkv(48, 32);
  gemm_qkv<<<gqkv, 256, 0, stream>>>(x_bf, WpT, bp, qkb, Vtb);

  attn_v6<<<1024, 256, 0, stream>>>(qkb, Vtb, y);

  dim3 go(16, 32);
  gemm_out_res<<<go, 256, 0, stream>>>(y, WoT, bo, x, z);

  ln_kernel<<<4096, 256, 0, stream>>>(z, gamma, beta, out);
}